// Round 6
// baseline (549.559 us; speedup 1.0000x reference)
//
#include <hip/hip_runtime.h>
#include <hip/hip_bf16.h>

#define N_NODES 50000
#define N_EDGES 800000
#define N_REL   4
#define D       128
#define NE      (N_REL * N_EDGES)   // 3200000 edges

#define C_CHUNKS 16
#define CHUNK_E  (NE / C_CHUNKS)    // 200000 edges per chunk (rel = chunk>>2)
#define G_RANGES 16
#define RPG      (N_NODES / G_RANGES) // 3125 rows per range

#define NCNT     (N_NODES * C_CHUNKS) // 800000 (row,chunk) cells
#define SCAN_CHUNK 1024
#define NBLK ((NCNT + SCAN_CHUNK - 1) / SCAN_CHUNK)   // 782

// ---------------------------------------------------------------------------
// ws layout (bytes) — no global atomics anywhere, no memset needed:
//   CNT   @ 0        : 800000 i32 counts -> scanned in place   3,200,000
//   WT    @ 3200000  : 5*128*128 bf16 [seg][n][k]                163,840
//   BSUM  @ 3364096  : 782 i32
//   BOFF  @ 3368192  : 782 i32
//   INV2  @ 3372288  : 200000 f32 inv_sqrt [node*4+rel]          800,000
//   EREC  @ 4172288  : 3.2M int2 (pc = r*N+col, raw val)      25,600,000
//   Y     @ 29772288 : 4*50000*128 bf16                       51,200,000
//   XB    @ 80972288 : 50000*128 bf16; RANK aliases after mm  12,800,000
// total ~93.8 MB (well under the 103.2 MB proven watermark)
// ---------------------------------------------------------------------------
#define OFF_CNT   0
#define OFF_WT    3200000
#define OFF_BSUM  3364096
#define OFF_BOFF  3368192
#define OFF_INV2  3372288
#define OFF_EREC  4172288
#define OFF_Y     29772288
#define OFF_XB    80972288

typedef __attribute__((ext_vector_type(8))) short bf16x8;
typedef __attribute__((ext_vector_type(4))) float f32x4;

__device__ inline unsigned short f2bf(float f) {
    unsigned u = __float_as_uint(f);
    u += 0x7fffu + ((u >> 16) & 1u);
    return (unsigned short)(u >> 16);
}

// --- prep: X f32 -> bf16 ---------------------------------------------------
__global__ __launch_bounds__(256) void k_prep_x(const float* __restrict__ X,
                                                unsigned short* __restrict__ Xb) {
    int id = blockIdx.x * 256 + threadIdx.x;
    float4 v = *(const float4*)(X + (size_t)id * 4);
    ushort4 h;
    h.x = f2bf(v.x); h.y = f2bf(v.y); h.z = f2bf(v.z); h.w = f2bf(v.w);
    *(ushort4*)(Xb + (size_t)id * 4) = h;
}

// --- prep: W (f32 [k][n]) -> Wt bf16 [seg][n][k] ---------------------------
__global__ __launch_bounds__(256) void k_prep_w(const float* __restrict__ Wself,
                                                const float* __restrict__ Wrel,
                                                unsigned short* __restrict__ Wt) {
    int id = blockIdx.x * 256 + threadIdx.x;
    int seg = id >> 14;
    int rem = id & 16383;
    int n = rem >> 7, k = rem & 127;
    float v = (seg == 0) ? Wself[k * 128 + n] : Wrel[(size_t)(seg - 1) * 16384 + k * 128 + n];
    Wt[id] = f2bf(v);
}

// --- LDS counting: block (chunk c, row-range g). Zero global atomics. ------
// Emits per-edge local rank and cnt[row][c] (plain stores).
__global__ __launch_bounds__(256) void k_count(const int* __restrict__ rows,
                                               int* __restrict__ cnt,
                                               unsigned int* __restrict__ rank) {
    __shared__ int lc[RPG];                      // 12.5 KB
    const int c = blockIdx.x >> 4;
    const int g = blockIdx.x & 15;
    const int rbase = g * RPG;
    for (int i = threadIdx.x; i < RPG; i += 256) lc[i] = 0;
    __syncthreads();
    const int t0 = c * CHUNK_E;
    for (int t = t0 + threadIdx.x; t < t0 + CHUNK_E; t += 256) {
        int row = rows[t];
        unsigned int lr = (unsigned int)(row - rbase);
        if (lr < (unsigned int)RPG) {
            int old = atomicAdd(&lc[lr], 1);     // LDS atomic — on-CU, cheap
            rank[t] = (unsigned int)old;
        }
    }
    __syncthreads();
    for (int i = threadIdx.x; i < RPG; i += 256)
        cnt[(rbase + i) * C_CHUNKS + c] = lc[i];
}

// --- scan over 800000 (row,chunk) counts, in place -------------------------
__global__ __launch_bounds__(256) void k_scanA(int* __restrict__ bst,
                                               int* __restrict__ bsum) {
    __shared__ int s[256];
    int t = threadIdx.x;
    int base = blockIdx.x * SCAN_CHUNK + t * 4;
    int v0 = 0, v1 = 0, v2 = 0, v3 = 0;
    if (base + 3 < NCNT) {
        int4 v = *(const int4*)(bst + base);
        v0 = v.x; v1 = v.y; v2 = v.z; v3 = v.w;
    } else {
        if (base     < NCNT) v0 = bst[base];
        if (base + 1 < NCNT) v1 = bst[base + 1];
        if (base + 2 < NCNT) v2 = bst[base + 2];
        if (base + 3 < NCNT) v3 = bst[base + 3];
    }
    int tsum = v0 + v1 + v2 + v3;
    s[t] = tsum;
    __syncthreads();
    for (int off = 1; off < 256; off <<= 1) {
        int x = (t >= off) ? s[t - off] : 0;
        __syncthreads();
        s[t] += x;
        __syncthreads();
    }
    int excl = s[t] - tsum;
    if (base     < NCNT) bst[base]     = excl;
    if (base + 1 < NCNT) bst[base + 1] = excl + v0;
    if (base + 2 < NCNT) bst[base + 2] = excl + v0 + v1;
    if (base + 3 < NCNT) bst[base + 3] = excl + v0 + v1 + v2;
    if (t == 255) bsum[blockIdx.x] = s[255];
}

__global__ __launch_bounds__(256) void k_scanB(const int* __restrict__ bsum,
                                               int* __restrict__ boff) {
    __shared__ int s[256];
    int t = threadIdx.x;
    int b = t * 4;
    int v0 = (b     < NBLK) ? bsum[b]     : 0;
    int v1 = (b + 1 < NBLK) ? bsum[b + 1] : 0;
    int v2 = (b + 2 < NBLK) ? bsum[b + 2] : 0;
    int v3 = (b + 3 < NBLK) ? bsum[b + 3] : 0;
    int tsum = v0 + v1 + v2 + v3;
    s[t] = tsum;
    __syncthreads();
    for (int off = 1; off < 256; off <<= 1) {
        int x = (t >= off) ? s[t - off] : 0;
        __syncthreads();
        s[t] += x;
        __syncthreads();
    }
    int excl = s[t] - tsum;
    if (b     < NBLK) boff[b]     = excl;
    if (b + 1 < NBLK) boff[b + 1] = excl + v0;
    if (b + 2 < NBLK) boff[b + 2] = excl + v0 + v1;
    if (b + 3 < NBLK) boff[b + 3] = excl + v0 + v1 + v2;
}

__global__ __launch_bounds__(256) void k_scanC(int* __restrict__ bst,
                                               const int* __restrict__ boff) {
    int t = threadIdx.x;
    int base = blockIdx.x * SCAN_CHUNK + t * 4;
    int add = boff[blockIdx.x];
#pragma unroll
    for (int q = 0; q < 4; q++) {
        int idx = base + q;
        if (idx < NCNT) bst[idx] += add;
    }
}

// --- fill CSR records, fully atomic-free -----------------------------------
__global__ __launch_bounds__(256) void k_fill(const int* __restrict__ rows,
                                              const int* __restrict__ cols,
                                              const float* __restrict__ vals,
                                              const int* __restrict__ bst,
                                              const unsigned int* __restrict__ rank,
                                              int2* __restrict__ erec) {
    int t = blockIdx.x * 256 + threadIdx.x;
    if (t >= NE) return;
    int c = t / CHUNK_E;                 // chunk (const-div)
    int r = c >> 2;                      // relation
    int row = rows[t], col = cols[t];
    int pos = bst[row * C_CHUNKS + c] + (int)rank[t];
    erec[pos] = make_int2(r * N_NODES + col, __float_as_int(vals[t]));
}

// --- degree: segmented sum over erec per row, per rel -> inv2 --------------
__global__ __launch_bounds__(256) void k_deg(const int* __restrict__ bst,
                                             const int2* __restrict__ erec,
                                             float* __restrict__ inv2) {
    const int wid = threadIdx.x >> 6, lane = threadIdx.x & 63;
    const int row = blockIdx.x * 4 + wid;
    if (row >= N_NODES) return;
    float acc[4] = {0.f, 0.f, 0.f, 0.f};
#pragma unroll
    for (int rel = 0; rel < 4; rel++) {
        int s = bst[row * C_CHUNKS + rel * 4];
        int e = (rel < 3) ? bst[row * C_CHUNKS + rel * 4 + 4]
                          : ((row + 1 < N_NODES) ? bst[(row + 1) * C_CHUNKS] : NE);
        for (int i = s + lane; i < e; i += 64)
            acc[rel] += __int_as_float(erec[i].y);
    }
#pragma unroll
    for (int rel = 0; rel < 4; rel++) {
        float v = acc[rel];
#pragma unroll
        for (int off = 32; off > 0; off >>= 1) v += __shfl_xor(v, off);
        if (lane == 0) inv2[row * 4 + rel] = rsqrtf(fmaxf(v, 1e-12f));
    }
}

// --- fused 5-panel MFMA GEMM -----------------------------------------------
__global__ __launch_bounds__(256) void k_mm(const unsigned short* __restrict__ Xb,
                                            const unsigned short* __restrict__ Wt,
                                            const float* __restrict__ bias,
                                            float* __restrict__ out,
                                            unsigned short* __restrict__ Yb) {
    const int seg = blockIdx.y;
    const int m0 = blockIdx.x * 128;
    const int tid = threadIdx.x;
    const int wave = tid >> 6, lane = tid & 63;
    const int wm = wave >> 1, wn = wave & 1;

    __shared__ unsigned short Xs[128][40];
    __shared__ unsigned short Ws[128][40];

    const f32x4 zero = {0.f, 0.f, 0.f, 0.f};
    f32x4 acc[4][4];
#pragma unroll
    for (int i = 0; i < 4; i++)
#pragma unroll
        for (int j = 0; j < 4; j++) acc[i][j] = zero;

    const unsigned short* Wseg = Wt + (size_t)seg * 16384;

    for (int k0 = 0; k0 < 128; k0 += 32) {
#pragma unroll
        for (int l = 0; l < 2; l++) {
            int id = tid + l * 256;
            int row = id >> 2, c4 = id & 3;
            int gr = m0 + row;
            int4 v = make_int4(0, 0, 0, 0);
            if (gr < N_NODES)
                v = *(const int4*)(Xb + (size_t)gr * 128 + k0 + c4 * 8);
            *(int4*)&Xs[row][c4 * 8] = v;
            int4 w = *(const int4*)(Wseg + (size_t)row * 128 + k0 + c4 * 8);
            *(int4*)&Ws[row][c4 * 8] = w;
        }
        __syncthreads();

        bf16x8 a[4], b[4];
        int kb = (lane >> 4) * 8;
        int lr = lane & 15;
#pragma unroll
        for (int i = 0; i < 4; i++)
            a[i] = *(const bf16x8*)&Xs[wm * 64 + i * 16 + lr][kb];
#pragma unroll
        for (int j = 0; j < 4; j++)
            b[j] = *(const bf16x8*)&Ws[wn * 64 + j * 16 + lr][kb];
#pragma unroll
        for (int i = 0; i < 4; i++)
#pragma unroll
            for (int j = 0; j < 4; j++)
                acc[i][j] = __builtin_amdgcn_mfma_f32_16x16x32_bf16(a[i], b[j], acc[i][j], 0, 0, 0);
        __syncthreads();
    }

    const int lrow = (lane >> 4) * 4;
    const int lcol = lane & 15;
    if (seg == 0) {
#pragma unroll
        for (int i = 0; i < 4; i++) {
#pragma unroll
            for (int j = 0; j < 4; j++) {
                int gc = wn * 64 + j * 16 + lcol;
                float bv = bias[gc];
#pragma unroll
                for (int v = 0; v < 4; v++) {
                    int gr = m0 + wm * 64 + i * 16 + lrow + v;
                    if (gr < N_NODES)
                        out[(size_t)gr * 128 + gc] = acc[i][j][v] + bv;
                }
            }
        }
    } else {
        unsigned short* Yseg = Yb + (size_t)(seg - 1) * N_NODES * 128;
#pragma unroll
        for (int i = 0; i < 4; i++) {
#pragma unroll
            for (int j = 0; j < 4; j++) {
                int gc = wn * 64 + j * 16 + lcol;
#pragma unroll
                for (int v = 0; v < 4; v++) {
                    int gr = m0 + wm * 64 + i * 16 + lrow + v;
                    if (gr < N_NODES)
                        Yseg[(size_t)gr * 128 + gc] = f2bf(acc[i][j][v]);
                }
            }
        }
    }
}

// --- gather: wave per row; per-lane coef precompute + readlane broadcast ---
__global__ __launch_bounds__(256, 4) void k_gather(const int* __restrict__ bst,
                                                   const int2* __restrict__ erec,
                                                   const float* __restrict__ inv2,
                                                   const unsigned int* __restrict__ Y2,
                                                   float* __restrict__ out) {
    const int wid = threadIdx.x >> 6;
    const int lane = threadIdx.x & 63;
    const int row = blockIdx.x * 4 + wid;
    if (row >= N_NODES) return;

    const int start = bst[row * C_CHUNKS];
    const int end = (row + 1 < N_NODES) ? bst[(row + 1) * C_CHUNKS] : NE;
    const float4 sv = *(const float4*)(inv2 + (size_t)row * 4);

    float ax = 0.f, ay = 0.f;
    for (int base = start; base < end; base += 64) {
        const int rem = end - base;
        int pcL = 0;
        float cfL = 0.f;
        if (lane < rem) {
            int2 rec = erec[base + lane];
            int pc = rec.x;
            int r = (int)((unsigned int)pc / (unsigned int)N_NODES);
            int col = pc - r * N_NODES;
            float selfinv = (r == 0) ? sv.x : (r == 1) ? sv.y : (r == 2) ? sv.z : sv.w;
            cfL = __int_as_float(rec.y) * selfinv * inv2[(size_t)col * 4 + r];
            pcL = pc;
        }
        if (rem >= 64) {
#pragma unroll
            for (int i = 0; i < 64; ++i) {
                int pc = __builtin_amdgcn_readlane(pcL, i);
                float cf = __int_as_float(__builtin_amdgcn_readlane(__float_as_int(cfL), i));
                unsigned int y = Y2[(size_t)pc * 64 + lane];
                ax = fmaf(cf, __uint_as_float(y << 16), ax);
                ay = fmaf(cf, __uint_as_float(y & 0xffff0000u), ay);
            }
        } else {
            for (int i = 0; i < rem; ++i) {
                int pc = __builtin_amdgcn_readlane(pcL, i);
                float cf = __int_as_float(__builtin_amdgcn_readlane(__float_as_int(cfL), i));
                unsigned int y = Y2[(size_t)pc * 64 + lane];
                ax = fmaf(cf, __uint_as_float(y << 16), ax);
                ay = fmaf(cf, __uint_as_float(y & 0xffff0000u), ay);
            }
        }
    }
    float2* op = (float2*)(out + (size_t)row * D) + lane;
    float2 o = *op;
    o.x += ax;
    o.y += ay;
    *op = o;
}

extern "C" void kernel_launch(void* const* d_in, const int* in_sizes, int n_in,
                              void* d_out, int out_size, void* d_ws, size_t ws_size,
                              hipStream_t stream) {
    const float* X     = (const float*)d_in[0];
    const int*   rows  = (const int*)d_in[1];
    const int*   cols  = (const int*)d_in[2];
    const float* vals  = (const float*)d_in[3];
    const float* Wrel  = (const float*)d_in[4];
    const float* Wself = (const float*)d_in[5];
    const float* bias  = (const float*)d_in[6];
    float* out = (float*)d_out;

    char* ws = (char*)d_ws;
    int*   cnt  = (int*)(ws + OFF_CNT);             // -> bst after scan
    unsigned short* Wt = (unsigned short*)(ws + OFF_WT);
    int*   bsum = (int*)(ws + OFF_BSUM);
    int*   boff = (int*)(ws + OFF_BOFF);
    float* inv2 = (float*)(ws + OFF_INV2);
    int2*  erec = (int2*)(ws + OFF_EREC);
    unsigned short* Yb = (unsigned short*)(ws + OFF_Y);
    unsigned short* Xb = (unsigned short*)(ws + OFF_XB);
    unsigned int* rank = (unsigned int*)(ws + OFF_XB);   // aliases Xb AFTER k_mm

    k_prep_x<<<6250, 256, 0, stream>>>(X, Xb);
    k_prep_w<<<320, 256, 0, stream>>>(Wself, Wrel, Wt);

    // GEMM first: Xb dies afterwards, its space becomes the rank array
    dim3 ggrid((N_NODES + 127) / 128, N_REL + 1);
    k_mm<<<ggrid, 256, 0, stream>>>(Xb, Wt, bias, out, Yb);

    k_count<<<C_CHUNKS * G_RANGES, 256, 0, stream>>>(rows, cnt, rank);
    k_scanA<<<NBLK, 256, 0, stream>>>(cnt, bsum);
    k_scanB<<<1, 256, 0, stream>>>(bsum, boff);
    k_scanC<<<NBLK, 256, 0, stream>>>(cnt, boff);

    k_fill<<<(NE + 255) / 256, 256, 0, stream>>>(rows, cols, vals, cnt, rank, erec);
    k_deg<<<(N_NODES + 3) / 4, 256, 0, stream>>>(cnt, erec, inv2);
    k_gather<<<(N_NODES + 3) / 4, 256, 0, stream>>>(cnt, erec, inv2,
                                                    (const unsigned int*)Yb, out);
}

// Round 7
// 401.600 us; speedup vs baseline: 1.3684x; 1.3684x over previous
//
#include <hip/hip_runtime.h>
#include <hip/hip_bf16.h>

#define N_NODES 50000
#define N_EDGES 800000
#define N_REL   4
#define D       128
#define NE      (N_REL * N_EDGES)   // 3200000 edges

#define S_SEG   64                  // edge segments; rel = seg>>4
#define SEG_E   (NE / S_SEG)        // 50000 edges per segment
#define G_RANGES 16
#define RPG     (N_NODES / G_RANGES) // 3125 rows per range

#define NCNT    (N_NODES * S_SEG)   // 3200000 (row,seg) cells
#define SCAN_CHUNK 4096
#define NBLK ((NCNT + SCAN_CHUNK - 1) / SCAN_CHUNK)   // 782

// ---------------------------------------------------------------------------
// ws layout (bytes) — zero global atomics anywhere, no memset needed:
//   BST   @ 0        : 3.2M i32 [row][seg] (transposed counts, scanned
//                      in place -> bin starts)                12,800,000
//   BSUM  @ 12800000 : 782 i32                                     3,200
//   BOFF  @ 12803200 : 782 i32                                     3,200
//   EREC  @ 12806400 : 3.2M int2 (pc=r*N+col, raw val)        25,600,000
//     (aliases: WT 5*128*128 bf16 during prep/mm;
//               CNTT 3.2M i32 [seg][row] during count/tr)
//   Y     @ 38406400 : 4*50000*128 bf16                       51,200,000
//   XB    @ 89606400 : 50000*128 bf16 during prep/mm;         12,800,000
//     (aliases after mm: RANK 3.2M u16 @ +0 = 6,400,000
//                        INV2 200000 f32 @ +6400000 = 800,000)
// total 102,406,400 B < 103,200,000 proven watermark (R1)
// ---------------------------------------------------------------------------
#define OFF_BST   0
#define OFF_BSUM  12800000
#define OFF_BOFF  12803200
#define OFF_EREC  12806400
#define OFF_Y     38406400
#define OFF_XB    89606400

typedef __attribute__((ext_vector_type(8))) short bf16x8;
typedef __attribute__((ext_vector_type(4))) float f32x4;

__device__ inline unsigned short f2bf(float f) {
    unsigned u = __float_as_uint(f);
    u += 0x7fffu + ((u >> 16) & 1u);
    return (unsigned short)(u >> 16);
}

// --- prep: X f32 -> bf16 ---------------------------------------------------
__global__ __launch_bounds__(256) void k_prep_x(const float* __restrict__ X,
                                                unsigned short* __restrict__ Xb) {
    int id = blockIdx.x * 256 + threadIdx.x;
    float4 v = *(const float4*)(X + (size_t)id * 4);
    ushort4 h;
    h.x = f2bf(v.x); h.y = f2bf(v.y); h.z = f2bf(v.z); h.w = f2bf(v.w);
    *(ushort4*)(Xb + (size_t)id * 4) = h;
}

// --- prep: W (f32 [k][n]) -> Wt bf16 [seg][n][k] ---------------------------
__global__ __launch_bounds__(256) void k_prep_w(const float* __restrict__ Wself,
                                                const float* __restrict__ Wrel,
                                                unsigned short* __restrict__ Wt) {
    int id = blockIdx.x * 256 + threadIdx.x;
    int seg = id >> 14;
    int rem = id & 16383;
    int n = rem >> 7, k = rem & 127;
    float v = (seg == 0) ? Wself[k * 128 + n] : Wrel[(size_t)(seg - 1) * 16384 + k * 128 + n];
    Wt[id] = f2bf(v);
}

// --- LDS counting: block (seg, row-range). 1024 blocks, 195 iters/thread ---
__global__ __launch_bounds__(256) void k_count(const int* __restrict__ rows,
                                               int* __restrict__ cntt,
                                               unsigned short* __restrict__ rank) {
    __shared__ int lc[RPG];                      // 12.5 KB
    const int seg = blockIdx.x >> 4;
    const int g = blockIdx.x & 15;
    const int rbase = g * RPG;
    for (int i = threadIdx.x; i < RPG; i += 256) lc[i] = 0;
    __syncthreads();
    const int t0 = seg * SEG_E;
    for (int t = t0 + threadIdx.x; t < t0 + SEG_E; t += 256) {
        int row = rows[t];
        unsigned int lr = (unsigned int)(row - rbase);
        if (lr < (unsigned int)RPG)
            rank[t] = (unsigned short)atomicAdd(&lc[lr], 1);   // LDS atomic
    }
    __syncthreads();
    for (int i = threadIdx.x; i < RPG; i += 256)
        cntt[seg * N_NODES + rbase + i] = lc[i];   // coalesced dump
}

// --- transpose cntt[seg][row] -> bst[row][seg], 64x64 tiles ----------------
__global__ __launch_bounds__(256) void k_tr(const int* __restrict__ cntt,
                                            int* __restrict__ bst) {
    __shared__ int tile[64][65];
    const int r0 = blockIdx.x * 64;
    const int l = threadIdx.x & 63;
    const int q = threadIdx.x >> 6;
#pragma unroll
    for (int p = 0; p < 16; ++p) {
        int seg = q * 16 + p;
        int row = r0 + l;
        tile[seg][l] = (row < N_NODES) ? cntt[(size_t)seg * N_NODES + row] : 0;
    }
    __syncthreads();
#pragma unroll
    for (int p = 0; p < 16; ++p) {
        int rr = q * 16 + p;
        int row = r0 + rr;
        if (row < N_NODES) bst[(size_t)row * S_SEG + l] = tile[l][rr];
    }
}

// --- scan over 3.2M (row,seg) counts, in place (16 cells/thread) -----------
__global__ __launch_bounds__(256) void k_scanA(int* __restrict__ bst,
                                               int* __restrict__ bsum) {
    __shared__ int s[256];
    int t = threadIdx.x;
    int base = blockIdx.x * SCAN_CHUNK + t * 16;
    int4 v[4];
    int tsum = 0;
#pragma unroll
    for (int q = 0; q < 4; ++q) {
        int idx = base + q * 4;
        if (idx < NCNT) v[q] = *(const int4*)(bst + idx);
        else v[q] = make_int4(0, 0, 0, 0);
        tsum += v[q].x + v[q].y + v[q].z + v[q].w;
    }
    s[t] = tsum;
    __syncthreads();
    for (int off = 1; off < 256; off <<= 1) {
        int x = (t >= off) ? s[t - off] : 0;
        __syncthreads();
        s[t] += x;
        __syncthreads();
    }
    int run = s[t] - tsum;
#pragma unroll
    for (int q = 0; q < 4; ++q) {
        int idx = base + q * 4;
        if (idx < NCNT) {
            int4 o;
            o.x = run; run += v[q].x;
            o.y = run; run += v[q].y;
            o.z = run; run += v[q].z;
            o.w = run; run += v[q].w;
            *(int4*)(bst + idx) = o;
        }
    }
    if (t == 255) bsum[blockIdx.x] = s[255];
}

__global__ __launch_bounds__(256) void k_scanB(const int* __restrict__ bsum,
                                               int* __restrict__ boff) {
    __shared__ int s[256];
    int t = threadIdx.x;
    int b = t * 4;
    int v0 = (b     < NBLK) ? bsum[b]     : 0;
    int v1 = (b + 1 < NBLK) ? bsum[b + 1] : 0;
    int v2 = (b + 2 < NBLK) ? bsum[b + 2] : 0;
    int v3 = (b + 3 < NBLK) ? bsum[b + 3] : 0;
    int tsum = v0 + v1 + v2 + v3;
    s[t] = tsum;
    __syncthreads();
    for (int off = 1; off < 256; off <<= 1) {
        int x = (t >= off) ? s[t - off] : 0;
        __syncthreads();
        s[t] += x;
        __syncthreads();
    }
    int excl = s[t] - tsum;
    if (b     < NBLK) boff[b]     = excl;
    if (b + 1 < NBLK) boff[b + 1] = excl + v0;
    if (b + 2 < NBLK) boff[b + 2] = excl + v0 + v1;
    if (b + 3 < NBLK) boff[b + 3] = excl + v0 + v1 + v2;
}

__global__ __launch_bounds__(256) void k_scanC(int* __restrict__ bst,
                                               const int* __restrict__ boff) {
    int t = threadIdx.x;
    int base = blockIdx.x * SCAN_CHUNK + t * 16;
    int add = boff[blockIdx.x];
#pragma unroll
    for (int q = 0; q < 4; ++q) {
        int idx = base + q * 4;
        if (idx < NCNT) {
            int4 v = *(const int4*)(bst + idx);
            v.x += add; v.y += add; v.z += add; v.w += add;
            *(int4*)(bst + idx) = v;
        }
    }
}

// --- fill CSR records, fully atomic-free -----------------------------------
__global__ __launch_bounds__(256) void k_fill(const int* __restrict__ rows,
                                              const int* __restrict__ cols,
                                              const float* __restrict__ vals,
                                              const int* __restrict__ bst,
                                              const unsigned short* __restrict__ rank,
                                              int2* __restrict__ erec) {
    int t = blockIdx.x * 256 + threadIdx.x;
    if (t >= NE) return;
    int seg = t / SEG_E;                 // const-div
    int r = seg >> 4;                    // relation
    int row = rows[t], col = cols[t];
    int pos = bst[(size_t)row * S_SEG + seg] + (int)rank[t];
    erec[pos] = make_int2(r * N_NODES + col, __float_as_int(vals[t]));
}

// --- degree: segmented sum over erec per row, per rel -> inv2 --------------
__global__ __launch_bounds__(256) void k_deg(const int* __restrict__ bst,
                                             const int2* __restrict__ erec,
                                             float* __restrict__ inv2) {
    const int wid = threadIdx.x >> 6, lane = threadIdx.x & 63;
    const int row = blockIdx.x * 4 + wid;
    if (row >= N_NODES) return;
    float acc[4] = {0.f, 0.f, 0.f, 0.f};
#pragma unroll
    for (int rel = 0; rel < 4; rel++) {
        int s = bst[(size_t)row * S_SEG + rel * 16];
        int e = (rel < 3) ? bst[(size_t)row * S_SEG + rel * 16 + 16]
                          : ((row + 1 < N_NODES) ? bst[(size_t)(row + 1) * S_SEG] : NE);
        for (int i = s + lane; i < e; i += 64)
            acc[rel] += __int_as_float(erec[i].y);
    }
#pragma unroll
    for (int rel = 0; rel < 4; rel++) {
        float v = acc[rel];
#pragma unroll
        for (int off = 32; off > 0; off >>= 1) v += __shfl_xor(v, off);
        if (lane == 0) inv2[row * 4 + rel] = rsqrtf(fmaxf(v, 1e-12f));
    }
}

// --- fused 5-panel MFMA GEMM -----------------------------------------------
__global__ __launch_bounds__(256) void k_mm(const unsigned short* __restrict__ Xb,
                                            const unsigned short* __restrict__ Wt,
                                            const float* __restrict__ bias,
                                            float* __restrict__ out,
                                            unsigned short* __restrict__ Yb) {
    const int seg = blockIdx.y;
    const int m0 = blockIdx.x * 128;
    const int tid = threadIdx.x;
    const int wave = tid >> 6, lane = tid & 63;
    const int wm = wave >> 1, wn = wave & 1;

    __shared__ unsigned short Xs[128][40];
    __shared__ unsigned short Ws[128][40];

    const f32x4 zero = {0.f, 0.f, 0.f, 0.f};
    f32x4 acc[4][4];
#pragma unroll
    for (int i = 0; i < 4; i++)
#pragma unroll
        for (int j = 0; j < 4; j++) acc[i][j] = zero;

    const unsigned short* Wseg = Wt + (size_t)seg * 16384;

    for (int k0 = 0; k0 < 128; k0 += 32) {
#pragma unroll
        for (int l = 0; l < 2; l++) {
            int id = tid + l * 256;
            int row = id >> 2, c4 = id & 3;
            int gr = m0 + row;
            int4 v = make_int4(0, 0, 0, 0);
            if (gr < N_NODES)
                v = *(const int4*)(Xb + (size_t)gr * 128 + k0 + c4 * 8);
            *(int4*)&Xs[row][c4 * 8] = v;
            int4 w = *(const int4*)(Wseg + (size_t)row * 128 + k0 + c4 * 8);
            *(int4*)&Ws[row][c4 * 8] = w;
        }
        __syncthreads();

        bf16x8 a[4], b[4];
        int kb = (lane >> 4) * 8;
        int lr = lane & 15;
#pragma unroll
        for (int i = 0; i < 4; i++)
            a[i] = *(const bf16x8*)&Xs[wm * 64 + i * 16 + lr][kb];
#pragma unroll
        for (int j = 0; j < 4; j++)
            b[j] = *(const bf16x8*)&Ws[wn * 64 + j * 16 + lr][kb];
#pragma unroll
        for (int i = 0; i < 4; i++)
#pragma unroll
            for (int j = 0; j < 4; j++)
                acc[i][j] = __builtin_amdgcn_mfma_f32_16x16x32_bf16(a[i], b[j], acc[i][j], 0, 0, 0);
        __syncthreads();
    }

    const int lrow = (lane >> 4) * 4;
    const int lcol = lane & 15;
    if (seg == 0) {
#pragma unroll
        for (int i = 0; i < 4; i++) {
#pragma unroll
            for (int j = 0; j < 4; j++) {
                int gc = wn * 64 + j * 16 + lcol;
                float bv = bias[gc];
#pragma unroll
                for (int v = 0; v < 4; v++) {
                    int gr = m0 + wm * 64 + i * 16 + lrow + v;
                    if (gr < N_NODES)
                        out[(size_t)gr * 128 + gc] = acc[i][j][v] + bv;
                }
            }
        }
    } else {
        unsigned short* Yseg = Yb + (size_t)(seg - 1) * N_NODES * 128;
#pragma unroll
        for (int i = 0; i < 4; i++) {
#pragma unroll
            for (int j = 0; j < 4; j++) {
                int gc = wn * 64 + j * 16 + lcol;
#pragma unroll
                for (int v = 0; v < 4; v++) {
                    int gr = m0 + wm * 64 + i * 16 + lrow + v;
                    if (gr < N_NODES)
                        Yseg[(size_t)gr * 128 + gc] = f2bf(acc[i][j][v]);
                }
            }
        }
    }
}

// --- gather: wave per row; per-lane coef precompute + readlane broadcast ---
__global__ __launch_bounds__(256, 4) void k_gather(const int* __restrict__ bst,
                                                   const int2* __restrict__ erec,
                                                   const float* __restrict__ inv2,
                                                   const unsigned int* __restrict__ Y2,
                                                   float* __restrict__ out) {
    const int wid = threadIdx.x >> 6;
    const int lane = threadIdx.x & 63;
    const int row = blockIdx.x * 4 + wid;
    if (row >= N_NODES) return;

    const int start = bst[(size_t)row * S_SEG];
    const int end = (row + 1 < N_NODES) ? bst[(size_t)(row + 1) * S_SEG] : NE;
    const float4 sv = *(const float4*)(inv2 + (size_t)row * 4);

    float ax = 0.f, ay = 0.f;
    for (int base = start; base < end; base += 64) {
        const int rem = end - base;
        int pcL = 0;
        float cfL = 0.f;
        if (lane < rem) {
            int2 rec = erec[base + lane];
            int pc = rec.x;
            int r = (int)((unsigned int)pc / (unsigned int)N_NODES);
            int col = pc - r * N_NODES;
            float selfinv = (r == 0) ? sv.x : (r == 1) ? sv.y : (r == 2) ? sv.z : sv.w;
            cfL = __int_as_float(rec.y) * selfinv * inv2[(size_t)col * 4 + r];
            pcL = pc;
        }
        if (rem >= 64) {
#pragma unroll
            for (int i = 0; i < 64; ++i) {
                int pc = __builtin_amdgcn_readlane(pcL, i);
                float cf = __int_as_float(__builtin_amdgcn_readlane(__float_as_int(cfL), i));
                unsigned int y = Y2[(size_t)pc * 64 + lane];
                ax = fmaf(cf, __uint_as_float(y << 16), ax);
                ay = fmaf(cf, __uint_as_float(y & 0xffff0000u), ay);
            }
        } else {
            for (int i = 0; i < rem; ++i) {
                int pc = __builtin_amdgcn_readlane(pcL, i);
                float cf = __int_as_float(__builtin_amdgcn_readlane(__float_as_int(cfL), i));
                unsigned int y = Y2[(size_t)pc * 64 + lane];
                ax = fmaf(cf, __uint_as_float(y << 16), ax);
                ay = fmaf(cf, __uint_as_float(y & 0xffff0000u), ay);
            }
        }
    }
    float2* op = (float2*)(out + (size_t)row * D) + lane;
    float2 o = *op;
    o.x += ax;
    o.y += ay;
    *op = o;
}

extern "C" void kernel_launch(void* const* d_in, const int* in_sizes, int n_in,
                              void* d_out, int out_size, void* d_ws, size_t ws_size,
                              hipStream_t stream) {
    const float* X     = (const float*)d_in[0];
    const int*   rows  = (const int*)d_in[1];
    const int*   cols  = (const int*)d_in[2];
    const float* vals  = (const float*)d_in[3];
    const float* Wrel  = (const float*)d_in[4];
    const float* Wself = (const float*)d_in[5];
    const float* bias  = (const float*)d_in[6];
    float* out = (float*)d_out;

    char* ws = (char*)d_ws;
    int*   bst  = (int*)(ws + OFF_BST);
    int*   bsum = (int*)(ws + OFF_BSUM);
    int*   boff = (int*)(ws + OFF_BOFF);
    int2*  erec = (int2*)(ws + OFF_EREC);
    int*   cntt = (int*)(ws + OFF_EREC);            // aliases erec (pre-fill)
    unsigned short* Wt = (unsigned short*)(ws + OFF_EREC); // aliases (pre-count)
    unsigned short* Yb = (unsigned short*)(ws + OFF_Y);
    unsigned short* Xb = (unsigned short*)(ws + OFF_XB);
    unsigned short* rank = (unsigned short*)(ws + OFF_XB); // aliases Xb after mm
    float* inv2 = (float*)(ws + OFF_XB + 6400000);         // after rank

    k_prep_x<<<6250, 256, 0, stream>>>(X, Xb);
    k_prep_w<<<320, 256, 0, stream>>>(Wself, Wrel, Wt);

    // GEMM first: Xb and Wt die afterwards; their space -> rank / cntt
    dim3 ggrid((N_NODES + 127) / 128, N_REL + 1);
    k_mm<<<ggrid, 256, 0, stream>>>(Xb, Wt, bias, out, Yb);

    k_count<<<S_SEG * G_RANGES, 256, 0, stream>>>(rows, cntt, rank);
    k_tr<<<(N_NODES + 63) / 64, 256, 0, stream>>>(cntt, bst);
    k_scanA<<<NBLK, 256, 0, stream>>>(bst, bsum);
    k_scanB<<<1, 256, 0, stream>>>(bsum, boff);
    k_scanC<<<NBLK, 256, 0, stream>>>(bst, boff);

    k_fill<<<(NE + 255) / 256, 256, 0, stream>>>(rows, cols, vals, bst, rank, erec);
    k_deg<<<(N_NODES + 3) / 4, 256, 0, stream>>>(bst, erec, inv2);
    k_gather<<<(N_NODES + 3) / 4, 256, 0, stream>>>(bst, erec, inv2,
                                                    (const unsigned int*)Yb, out);
}

// Round 8
// 368.076 us; speedup vs baseline: 1.4931x; 1.0911x over previous
//
#include <hip/hip_runtime.h>
#include <hip/hip_bf16.h>

#define N_NODES 50000
#define N_EDGES 800000
#define N_REL   4
#define D       128
#define NE      (N_REL * N_EDGES)   // 3200000 edges

#define S_SEG   64                  // edge segments; rel = seg>>4
#define SEG_E   (NE / S_SEG)        // 50000 edges per segment
#define G_RANGES 8
#define RPG     (N_NODES / G_RANGES) // 6250 rows per range

#define NCNT    (N_NODES * S_SEG)   // 3200000 (row,seg) cells
#define SCAN_CHUNK 4096
#define NBLK ((NCNT + SCAN_CHUNK - 1) / SCAN_CHUNK)   // 782

// ---------------------------------------------------------------------------
// ws layout (bytes) — zero global atomics, no memset, no Xb (mm reads X f32):
//   BST   @ 0        : 3.2M i32 [row][seg] counts->starts     12,800,000
//   BSUM  @ 12800000 : 782 i32 (pad 3200)
//   BOFF  @ 12803200 : 782 i32 (pad 3200)
//   EREC  @ 12806400 : 3.2M int2 (pc=r*N+col, raw val)        25,600,000
//     (aliases, sequentially dead: WT bf16 5*128*128 [prep_w..mm];
//      CNTT 64x50000 i32 [count..tr])
//   Y     @ 38406400 : 4*50000*128 bf16                       51,200,000
//   RANK  @ 89606400 : 3.2M u16                                6,400,000
//   INV2  @ 96006400 : 200000 f32                                800,000
// total 96.8 MB < 103.2 MB proven watermark (R1)
// ---------------------------------------------------------------------------
#define OFF_BST   0
#define OFF_BSUM  12800000
#define OFF_BOFF  12803200
#define OFF_EREC  12806400
#define OFF_Y     38406400
#define OFF_RANK  89606400
#define OFF_INV2  96006400

typedef __attribute__((ext_vector_type(8))) short bf16x8;
typedef __attribute__((ext_vector_type(4))) float f32x4;

__device__ inline unsigned short f2bf(float f) {
    unsigned u = __float_as_uint(f);
    u += 0x7fffu + ((u >> 16) & 1u);
    return (unsigned short)(u >> 16);
}

// --- prep: W (f32 [k][n]) -> Wt bf16 [seg][n][k] ---------------------------
__global__ __launch_bounds__(256) void k_prep_w(const float* __restrict__ Wself,
                                                const float* __restrict__ Wrel,
                                                unsigned short* __restrict__ Wt) {
    int id = blockIdx.x * 256 + threadIdx.x;
    int seg = id >> 14;
    int rem = id & 16383;
    int n = rem >> 7, k = rem & 127;
    float v = (seg == 0) ? Wself[k * 128 + n] : Wrel[(size_t)(seg - 1) * 16384 + k * 128 + n];
    Wt[id] = f2bf(v);
}

// --- fused 5-panel MFMA GEMM: 64-row tile, X staged once, W from global ----
// seg 0: out = X@Wself + bias (f32) ; seg r: Y[r-1] = X@Wrel[r-1] (bf16)
__global__ __launch_bounds__(256) void k_mm(const float* __restrict__ X,
                                            const unsigned short* __restrict__ Wt,
                                            const float* __restrict__ bias,
                                            float* __restrict__ out,
                                            unsigned short* __restrict__ Yb) {
    const int m0 = blockIdx.x * 64;
    const int tid = threadIdx.x;
    const int wave = tid >> 6, lane = tid & 63;
    const int wm = wave >> 1, wn = wave & 1;

    __shared__ unsigned short Xs[64][136];   // 272B row stride (16B-aligned)

    // stage X tile 64x128 f32 -> bf16, once
#pragma unroll
    for (int l = 0; l < 8; l++) {
        int c = tid + l * 256;          // 2048 float4 chunks
        int row = c >> 5, c4 = c & 31;
        int gr = m0 + row;
        float4 v = make_float4(0.f, 0.f, 0.f, 0.f);
        if (gr < N_NODES) v = *(const float4*)(X + (size_t)gr * 128 + c4 * 4);
        ushort4 h;
        h.x = f2bf(v.x); h.y = f2bf(v.y); h.z = f2bf(v.z); h.w = f2bf(v.w);
        *(ushort4*)&Xs[row][c4 * 4] = h;
    }
    __syncthreads();

    const int lr = lane & 15;
    const int kb = (lane >> 4) * 8;
    const int lrow = (lane >> 4) * 4;
    const int lcol = lane & 15;
    const f32x4 zero = {0.f, 0.f, 0.f, 0.f};

    for (int seg = 0; seg < 5; seg++) {
        const unsigned short* Wseg = Wt + (size_t)seg * 16384;
        f32x4 acc[2][4];
#pragma unroll
        for (int i = 0; i < 2; i++)
#pragma unroll
            for (int j = 0; j < 4; j++) acc[i][j] = zero;

#pragma unroll
        for (int k0 = 0; k0 < 128; k0 += 32) {
            bf16x8 a[2], b[4];
#pragma unroll
            for (int i = 0; i < 2; i++)
                a[i] = *(const bf16x8*)&Xs[wm * 32 + i * 16 + lr][k0 + kb];
#pragma unroll
            for (int j = 0; j < 4; j++)
                b[j] = *(const bf16x8*)(Wseg + (size_t)(wn * 64 + j * 16 + lr) * 128 + k0 + kb);
#pragma unroll
            for (int i = 0; i < 2; i++)
#pragma unroll
                for (int j = 0; j < 4; j++)
                    acc[i][j] = __builtin_amdgcn_mfma_f32_16x16x32_bf16(a[i], b[j], acc[i][j], 0, 0, 0);
        }

        if (seg == 0) {
#pragma unroll
            for (int i = 0; i < 2; i++) {
#pragma unroll
                for (int j = 0; j < 4; j++) {
                    int gc = wn * 64 + j * 16 + lcol;
                    float bv = bias[gc];
#pragma unroll
                    for (int v = 0; v < 4; v++) {
                        int gr = m0 + wm * 32 + i * 16 + lrow + v;
                        if (gr < N_NODES)
                            out[(size_t)gr * 128 + gc] = acc[i][j][v] + bv;
                    }
                }
            }
        } else {
            unsigned short* Yseg = Yb + (size_t)(seg - 1) * N_NODES * 128;
#pragma unroll
            for (int i = 0; i < 2; i++) {
#pragma unroll
                for (int j = 0; j < 4; j++) {
                    int gc = wn * 64 + j * 16 + lcol;
#pragma unroll
                    for (int v = 0; v < 4; v++) {
                        int gr = m0 + wm * 32 + i * 16 + lrow + v;
                        if (gr < N_NODES)
                            Yseg[(size_t)gr * 128 + gc] = f2bf(acc[i][j][v]);
                    }
                }
            }
        }
    }
}

// --- LDS counting: block (seg, row-range). G=8, int4 loads -----------------
__global__ __launch_bounds__(256) void k_count(const int* __restrict__ rows,
                                               int* __restrict__ cntt,
                                               unsigned short* __restrict__ rank) {
    __shared__ int lc[RPG];                      // 25 KB
    const int seg = blockIdx.x >> 3;
    const int g = blockIdx.x & 7;
    const int rbase = g * RPG;
    for (int i = threadIdx.x; i < RPG; i += 256) lc[i] = 0;
    __syncthreads();
    const int4* r4 = (const int4*)(rows + (size_t)seg * SEG_E);
    const int n4 = SEG_E / 4;                    // 12500
    for (int i = threadIdx.x; i < n4; i += 256) {
        int4 v = r4[i];
        int t = seg * SEG_E + i * 4;
        unsigned int l0 = (unsigned int)(v.x - rbase);
        unsigned int l1 = (unsigned int)(v.y - rbase);
        unsigned int l2 = (unsigned int)(v.z - rbase);
        unsigned int l3 = (unsigned int)(v.w - rbase);
        if (l0 < (unsigned int)RPG) rank[t]     = (unsigned short)atomicAdd(&lc[l0], 1);
        if (l1 < (unsigned int)RPG) rank[t + 1] = (unsigned short)atomicAdd(&lc[l1], 1);
        if (l2 < (unsigned int)RPG) rank[t + 2] = (unsigned short)atomicAdd(&lc[l2], 1);
        if (l3 < (unsigned int)RPG) rank[t + 3] = (unsigned short)atomicAdd(&lc[l3], 1);
    }
    __syncthreads();
    for (int i = threadIdx.x; i < RPG; i += 256)
        cntt[(size_t)seg * N_NODES + rbase + i] = lc[i];
}

// --- transpose cntt[seg][row] -> bst[row][seg], 64x64 tiles ----------------
__global__ __launch_bounds__(256) void k_tr(const int* __restrict__ cntt,
                                            int* __restrict__ bst) {
    __shared__ int tile[64][65];
    const int r0 = blockIdx.x * 64;
    const int l = threadIdx.x & 63;
    const int q = threadIdx.x >> 6;
#pragma unroll
    for (int p = 0; p < 16; ++p) {
        int seg = q * 16 + p;
        int row = r0 + l;
        tile[seg][l] = (row < N_NODES) ? cntt[(size_t)seg * N_NODES + row] : 0;
    }
    __syncthreads();
#pragma unroll
    for (int p = 0; p < 16; ++p) {
        int rr = q * 16 + p;
        int row = r0 + rr;
        if (row < N_NODES) bst[(size_t)row * S_SEG + l] = tile[l][rr];
    }
}

// --- scan over 3.2M (row,seg) counts, in place (16 cells/thread) -----------
__global__ __launch_bounds__(256) void k_scanA(int* __restrict__ bst,
                                               int* __restrict__ bsum) {
    __shared__ int s[256];
    int t = threadIdx.x;
    int base = blockIdx.x * SCAN_CHUNK + t * 16;
    int4 v[4];
    int tsum = 0;
#pragma unroll
    for (int q = 0; q < 4; ++q) {
        int idx = base + q * 4;
        if (idx < NCNT) v[q] = *(const int4*)(bst + idx);
        else v[q] = make_int4(0, 0, 0, 0);
        tsum += v[q].x + v[q].y + v[q].z + v[q].w;
    }
    s[t] = tsum;
    __syncthreads();
    for (int off = 1; off < 256; off <<= 1) {
        int x = (t >= off) ? s[t - off] : 0;
        __syncthreads();
        s[t] += x;
        __syncthreads();
    }
    int run = s[t] - tsum;
#pragma unroll
    for (int q = 0; q < 4; ++q) {
        int idx = base + q * 4;
        if (idx < NCNT) {
            int4 o;
            o.x = run; run += v[q].x;
            o.y = run; run += v[q].y;
            o.z = run; run += v[q].z;
            o.w = run; run += v[q].w;
            *(int4*)(bst + idx) = o;
        }
    }
    if (t == 255) bsum[blockIdx.x] = s[255];
}

__global__ __launch_bounds__(256) void k_scanB(const int* __restrict__ bsum,
                                               int* __restrict__ boff) {
    __shared__ int s[256];
    int t = threadIdx.x;
    int b = t * 4;
    int v0 = (b     < NBLK) ? bsum[b]     : 0;
    int v1 = (b + 1 < NBLK) ? bsum[b + 1] : 0;
    int v2 = (b + 2 < NBLK) ? bsum[b + 2] : 0;
    int v3 = (b + 3 < NBLK) ? bsum[b + 3] : 0;
    int tsum = v0 + v1 + v2 + v3;
    s[t] = tsum;
    __syncthreads();
    for (int off = 1; off < 256; off <<= 1) {
        int x = (t >= off) ? s[t - off] : 0;
        __syncthreads();
        s[t] += x;
        __syncthreads();
    }
    int excl = s[t] - tsum;
    if (b     < NBLK) boff[b]     = excl;
    if (b + 1 < NBLK) boff[b + 1] = excl + v0;
    if (b + 2 < NBLK) boff[b + 2] = excl + v0 + v1;
    if (b + 3 < NBLK) boff[b + 3] = excl + v0 + v1 + v2;
}

__global__ __launch_bounds__(256) void k_scanC(int* __restrict__ bst,
                                               const int* __restrict__ boff) {
    int t = threadIdx.x;
    int base = blockIdx.x * SCAN_CHUNK + t * 16;
    int add = boff[blockIdx.x];
#pragma unroll
    for (int q = 0; q < 4; ++q) {
        int idx = base + q * 4;
        if (idx < NCNT) {
            int4 v = *(const int4*)(bst + idx);
            v.x += add; v.y += add; v.z += add; v.w += add;
            *(int4*)(bst + idx) = v;
        }
    }
}

// --- fill CSR records, fully atomic-free -----------------------------------
__global__ __launch_bounds__(256) void k_fill(const int* __restrict__ rows,
                                              const int* __restrict__ cols,
                                              const float* __restrict__ vals,
                                              const int* __restrict__ bst,
                                              const unsigned short* __restrict__ rank,
                                              int2* __restrict__ erec) {
    int t = blockIdx.x * 256 + threadIdx.x;
    if (t >= NE) return;
    int seg = t / SEG_E;                 // const-div
    int r = seg >> 4;                    // relation
    int row = rows[t], col = cols[t];
    int pos = bst[(size_t)row * S_SEG + seg] + (int)rank[t];
    erec[pos] = make_int2(r * N_NODES + col, __float_as_int(vals[t]));
}

// --- degree: thread per (row,rel), contiguous record-run sum ---------------
__global__ __launch_bounds__(256) void k_deg(const int* __restrict__ bst,
                                             const int2* __restrict__ erec,
                                             float* __restrict__ inv2) {
    int t = blockIdx.x * 256 + threadIdx.x;
    if (t >= N_NODES * 4) return;
    int row = t >> 2, rel = t & 3;
    int s = bst[(size_t)row * S_SEG + rel * 16];
    int e = (rel < 3) ? bst[(size_t)row * S_SEG + rel * 16 + 16]
                      : ((row + 1 < N_NODES) ? bst[(size_t)(row + 1) * S_SEG] : NE);
    float acc = 0.f;
    for (int i = s; i < e; ++i) acc += __int_as_float(erec[i].y);
    inv2[t] = rsqrtf(fmaxf(acc, 1e-12f));
}

// --- gather: wave per row; per-lane coef precompute + readlane broadcast ---
__global__ __launch_bounds__(256, 8) void k_gather(const int* __restrict__ bst,
                                                   const int2* __restrict__ erec,
                                                   const float* __restrict__ inv2,
                                                   const unsigned int* __restrict__ Y2,
                                                   float* __restrict__ out) {
    const int wid = threadIdx.x >> 6;
    const int lane = threadIdx.x & 63;
    const int row = blockIdx.x * 4 + wid;
    if (row >= N_NODES) return;

    const int start = bst[(size_t)row * S_SEG];
    const int end = (row + 1 < N_NODES) ? bst[(size_t)(row + 1) * S_SEG] : NE;
    const float4 sv = *(const float4*)(inv2 + (size_t)row * 4);

    float ax = 0.f, ay = 0.f;
    for (int base = start; base < end; base += 64) {
        const int rem = end - base;
        int pcL = 0;
        float cfL = 0.f;
        if (lane < rem) {
            int2 rec = erec[base + lane];
            int pc = rec.x;
            int r = (int)((unsigned int)pc / (unsigned int)N_NODES);
            int col = pc - r * N_NODES;
            float selfinv = (r == 0) ? sv.x : (r == 1) ? sv.y : (r == 2) ? sv.z : sv.w;
            cfL = __int_as_float(rec.y) * selfinv * inv2[(size_t)col * 4 + r];
            pcL = pc;
        }
        if (rem >= 64) {
#pragma unroll
            for (int i = 0; i < 64; ++i) {
                int pc = __builtin_amdgcn_readlane(pcL, i);
                float cf = __int_as_float(__builtin_amdgcn_readlane(__float_as_int(cfL), i));
                unsigned int y = Y2[(size_t)pc * 64 + lane];
                ax = fmaf(cf, __uint_as_float(y << 16), ax);
                ay = fmaf(cf, __uint_as_float(y & 0xffff0000u), ay);
            }
        } else {
            for (int i = 0; i < rem; ++i) {
                int pc = __builtin_amdgcn_readlane(pcL, i);
                float cf = __int_as_float(__builtin_amdgcn_readlane(__float_as_int(cfL), i));
                unsigned int y = Y2[(size_t)pc * 64 + lane];
                ax = fmaf(cf, __uint_as_float(y << 16), ax);
                ay = fmaf(cf, __uint_as_float(y & 0xffff0000u), ay);
            }
        }
    }
    float2* op = (float2*)(out + (size_t)row * D) + lane;
    float2 o = *op;
    o.x += ax;
    o.y += ay;
    *op = o;
}

extern "C" void kernel_launch(void* const* d_in, const int* in_sizes, int n_in,
                              void* d_out, int out_size, void* d_ws, size_t ws_size,
                              hipStream_t stream) {
    const float* X     = (const float*)d_in[0];
    const int*   rows  = (const int*)d_in[1];
    const int*   cols  = (const int*)d_in[2];
    const float* vals  = (const float*)d_in[3];
    const float* Wrel  = (const float*)d_in[4];
    const float* Wself = (const float*)d_in[5];
    const float* bias  = (const float*)d_in[6];
    float* out = (float*)d_out;

    char* ws = (char*)d_ws;
    int*   bst  = (int*)(ws + OFF_BST);
    int*   bsum = (int*)(ws + OFF_BSUM);
    int*   boff = (int*)(ws + OFF_BOFF);
    int2*  erec = (int2*)(ws + OFF_EREC);
    int*   cntt = (int*)(ws + OFF_EREC);                   // alias (count..tr)
    unsigned short* Wt = (unsigned short*)(ws + OFF_EREC); // alias (prep_w..mm)
    unsigned short* Yb = (unsigned short*)(ws + OFF_Y);
    unsigned short* rank = (unsigned short*)(ws + OFF_RANK);
    float* inv2 = (float*)(ws + OFF_INV2);

    k_prep_w<<<320, 256, 0, stream>>>(Wself, Wrel, Wt);

    // GEMM consumes Wt; afterwards the EREC region is reused by cntt/erec
    k_mm<<<(N_NODES + 63) / 64, 256, 0, stream>>>(X, Wt, bias, out, Yb);

    k_count<<<S_SEG * G_RANGES, 256, 0, stream>>>(rows, cntt, rank);
    k_tr<<<(N_NODES + 63) / 64, 256, 0, stream>>>(cntt, bst);
    k_scanA<<<NBLK, 256, 0, stream>>>(bst, bsum);
    k_scanB<<<1, 256, 0, stream>>>(bsum, boff);
    k_scanC<<<NBLK, 256, 0, stream>>>(bst, boff);

    k_fill<<<(NE + 255) / 256, 256, 0, stream>>>(rows, cols, vals, bst, rank, erec);
    k_deg<<<(N_NODES * 4 + 255) / 256, 256, 0, stream>>>(bst, erec, inv2);
    k_gather<<<(N_NODES + 3) / 4, 256, 0, stream>>>(bst, erec, inv2,
                                                    (const unsigned int*)Yb, out);
}